// Round 4
// baseline (576.068 us; speedup 1.0000x reference)
//
#include <hip/hip_runtime.h>

typedef unsigned int  u32;
typedef unsigned short u16;
typedef __attribute__((ext_vector_type(8))) _Float16 h8;   // MFMA A/B frag: 8 fp16 = 4 VGPR
typedef __attribute__((ext_vector_type(4))) float    f4;   // MFMA C/D frag

#define RS    136    // padded row stride (fp16): 272B rows, 16B-aligned
#define PRS   40     // row stride for vde weights (K=18 padded to 32, stored 40)
#define PIXB  128    // pixels per block (4 waves x 32 pixels)
#define WOFF  5120   // vde region size (halves)
#define FULL  17408  // 128*RS: one full layer tile (halves)
#define MFMA16 __builtin_amdgcn_mfma_f32_16x16x32_f16

__device__ __forceinline__ u16 f2h(float f) {
  _Float16 h = (_Float16)f;
  return __builtin_bit_cast(u16, h);
}
__device__ __forceinline__ float h2f(u16 u) {
  return (float)__builtin_bit_cast(_Float16, u);
}

// ---------------------------------------------------------------------------
// Prep: fp16 weights, transposed to [out][in], padded rows.
// ws layout (fp16 elems): [0, 5120)       vdeT [128][40] (k<18 valid)
//   [5120 + j*17408), j=0..11 : 12 x [128][136]
//   j: 0..2 vh, 3..8 hid, 9 headW0, 10 headW1, 11 headW2 (rows>=16 / n>=4 zero)
// Total 214016 halves = 428032 B of d_ws.
// ---------------------------------------------------------------------------
__global__ __launch_bounds__(256) void rc_prep(
    const float* __restrict__ vde_W, const float* __restrict__ vh_W,
    const float* __restrict__ hid_W, const float* __restrict__ head_W0,
    const float* __restrict__ head_W1, const float* __restrict__ head_W2,
    u16* __restrict__ ws)
{
  const int TOT = WOFF + 12 * FULL;   // 214016
  int i = blockIdx.x * 256 + threadIdx.x;
  if (i >= TOT) return;
  float val = 0.f;
  if (i < WOFF) {
    int n = i / PRS, k = i - n * PRS;
    if (k < 18) val = vde_W[k * 128 + n];
  } else {
    int t = i - WOFF;
    int j = t / FULL;
    int rr = t - j * FULL;
    int n = rr / RS, k = rr - n * RS;
    if (k < 128) {
      if (j < 3)        val = vh_W[j * 16384 + k * 128 + n];
      else if (j < 9)   val = hid_W[(j - 3) * 16384 + k * 128 + n];
      else if (j == 9)  val = head_W0[k * 128 + n];
      else if (j == 10) val = head_W1[k * 128 + n];
      else              val = (n < 4) ? head_W2[k * 4 + n] : 0.f;
    }
  }
  ws[i] = f2h(val);
}

// ---------------------------------------------------------------------------
// Half-tile A-frag register set: 4 nt x 4 ks = 16 h8 = 64 VGPRs.
// ---------------------------------------------------------------------------
#define LOAD_HALF(AA, BASE) do {                                          \
  const u16* _bp = (BASE);                                                \
  _Pragma("unroll")                                                       \
  for (int nt4 = 0; nt4 < 4; ++nt4)                                       \
    _Pragma("unroll")                                                     \
    for (int ks = 0; ks < 4; ++ks)                                        \
      AA[nt4][ks] = *(const h8*)&_bp[(nt4 * 16 + r) * RS + ks * 32 + g * 8]; \
} while (0)

// Compute one half-tile (nt = HH*4 .. HH*4+3): bias-init from LDS (lgkm, does
// not drain vmcnt), 4 ks MFMA x 2 pixel-tiles, relu + mode handling, pack+store.
#define COMPUTE_HALF(HH, AA) do {                                         \
  _Pragma("unroll")                                                       \
  for (int nt4 = 0; nt4 < 4; ++nt4) {                                     \
    const int nt = (HH) * 4 + nt4;                                        \
    f4 bini = *(const f4*)&BL[blb + nt * 16 + 4 * g];                     \
    f4 acc0 = bini, acc1 = bini;                                          \
    _Pragma("unroll")                                                     \
    for (int ks = 0; ks < 4; ++ks) {                                      \
      acc0 = MFMA16(AA[nt4][ks], x0[ks], acc0, 0, 0, 0);                  \
      acc1 = MFMA16(AA[nt4][ks], x1[ks], acc1, 0, 0, 0);                  \
    }                                                                     \
    float v00 = fmaxf(acc0[0], 0.f), v01 = fmaxf(acc0[1], 0.f);           \
    float v02 = fmaxf(acc0[2], 0.f), v03 = fmaxf(acc0[3], 0.f);           \
    float v10 = fmaxf(acc1[0], 0.f), v11 = fmaxf(acc1[1], 0.f);           \
    float v12 = fmaxf(acc1[2], 0.f), v13 = fmaxf(acc1[3], 0.f);           \
    if (mode == 1) {                       /* capture vh in regs */       \
      vhp[0][nt][0] = (u32)f2h(v00) | ((u32)f2h(v01) << 16);              \
      vhp[0][nt][1] = (u32)f2h(v02) | ((u32)f2h(v03) << 16);              \
      vhp[1][nt][0] = (u32)f2h(v10) | ((u32)f2h(v11) << 16);              \
      vhp[1][nt][1] = (u32)f2h(v12) | ((u32)f2h(v13) << 16);              \
    } else {                                                              \
      if (mode == 2) {                     /* h = relu(out) * vh */       \
        v00 *= h2f((u16)(vhp[0][nt][0] & 0xffffu));                       \
        v01 *= h2f((u16)(vhp[0][nt][0] >> 16));                           \
        v02 *= h2f((u16)(vhp[0][nt][1] & 0xffffu));                       \
        v03 *= h2f((u16)(vhp[0][nt][1] >> 16));                           \
        v10 *= h2f((u16)(vhp[1][nt][0] & 0xffffu));                       \
        v11 *= h2f((u16)(vhp[1][nt][0] >> 16));                           \
        v12 *= h2f((u16)(vhp[1][nt][1] & 0xffffu));                       \
        v13 *= h2f((u16)(vhp[1][nt][1] >> 16));                           \
      }                                                                   \
      const int col = nt * 16 + 4 * g;                                    \
      *(uint2*)&X[xrow0 + col] = make_uint2(                              \
        (u32)f2h(v00) | ((u32)f2h(v01) << 16),                            \
        (u32)f2h(v02) | ((u32)f2h(v03) << 16));                           \
      *(uint2*)&X[xrow1 + col] = make_uint2(                              \
        (u32)f2h(v10) | ((u32)f2h(v11) << 16),                            \
        (u32)f2h(v12) | ((u32)f2h(v13) << 16));                           \
    }                                                                     \
  }                                                                       \
} while (0)

// ---------------------------------------------------------------------------
// Main fused kernel — cross-layer software pipeline, half-tile granularity:
//   issue H1(li) -> compute H0(li) -> issue H0(li+1) -> compute H1(li).
// Steady state: 16 weight loads always in flight; every vmcnt wait is covered
// by ~32 MFMA + epilogue of the other half. Biases come from LDS (lgkmcnt) so
// they never force a vmcnt drain. X rows are wave-private; raw s_barrier only
// keeps the block's waves layer-aligned for L1 weight-tile sharing.
// ---------------------------------------------------------------------------
__global__ __launch_bounds__(256, 2) void rc_main(
    const int*   __restrict__ vert,  const float* __restrict__ bary,
    const float* __restrict__ view,  const float* __restrict__ emb,
    const float* __restrict__ vde_b, const float* __restrict__ vh_b,
    const float* __restrict__ hid_b, const float* __restrict__ head_b0,
    const float* __restrict__ head_b1, const float* __restrict__ head_b2,
    const u16*   __restrict__ ws,    float* __restrict__ out)
{
  __shared__ __align__(16) u16   X[PIXB * RS];   // 34816 B activations
  __shared__ __align__(16) float BL[1664];       // 6656 B: all biases
  // BL: [0]=vde_b, [128..511]=vh_b, [512..1279]=hid_b, [1280]=head_b0,
  //     [1408]=head_b1, [1536..1539]=head_b2 (rest zero)

  const int tid  = threadIdx.x;
  const int lane = tid & 63;
  const int w    = tid >> 6;
  const int r    = lane & 15;       // pixel-within-tile (B col / D col); A row
  const int g    = lane >> 4;       // k-group; D row group
  const int pb   = w * 32;          // wave's first pixel row
  const size_t bpix = (size_t)blockIdx.x * PIXB;

  // ---- cooperative bias load into LDS
  for (int i = tid; i < 1664; i += 256) {
    float v;
    if      (i < 128)  v = vde_b[i];
    else if (i < 512)  v = vh_b[i - 128];
    else if (i < 1280) v = hid_b[i - 512];
    else if (i < 1408) v = head_b0[i - 1280];
    else if (i < 1536) v = head_b1[i - 1408];
    else if (i < 1540) v = head_b2[i - 1536];
    else               v = 0.f;
    BL[i] = v;
  }

  // ---- PE: lanes 0..31 compute their pixel's sin/cos encoding into X[row][0..32)
  if (lane < 32) {
    const int p = pb + lane;
    const float* vd = view + (bpix + p) * 3;
    const float SG0 = 6.28318530718f;   // 2pi / 0.9^0
    const float SG1 = 6.50777324f;      // 2pi / 0.9^(1/3)
    const float SG2 = 6.74038866f;      // 2pi / 0.9^(2/3)
    u32 pw[16];
#pragma unroll
    for (int i = 0; i < 3; ++i) {
      float x = vd[i];
      float s0 = __sinf(x * SG0), c0 = __cosf(x * SG0);
      float s1 = __sinf(x * SG1), c1 = __cosf(x * SG1);
      float s2 = __sinf(x * SG2), c2 = __cosf(x * SG2);
      pw[i * 3 + 0] = (u32)f2h(s0) | ((u32)f2h(s1) << 16);
      pw[i * 3 + 1] = (u32)f2h(s2) | ((u32)f2h(c0) << 16);
      pw[i * 3 + 2] = (u32)f2h(c1) | ((u32)f2h(c2) << 16);
    }
#pragma unroll
    for (int q = 9; q < 16; ++q) pw[q] = 0u;   // zero-pad k = 18..31
    uint4* dst = (uint4*)&X[p * RS];
#pragma unroll
    for (int q = 0; q < 4; ++q)
      dst[q] = make_uint4(pw[4*q], pw[4*q+1], pw[4*q+2], pw[4*q+3]);
  }
  __syncthreads();   // once; everything below is wave-private in X

  const int xrow0 = (pb +      r) * RS;
  const int xrow1 = (pb + 16 + r) * RS;

  h8 A0[4][4], A1[4][4];   // pipelined weight half-tiles (64 VGPRs each)

  // ---- L0: vde (K=18 padded to 32), prefetch layer0-H0 behind vde's loads
  {
    h8 Av[8];
#pragma unroll
    for (int nt = 0; nt < 8; ++nt)
      Av[nt] = *(const h8*)&ws[(nt * 16 + r) * PRS + g * 8];
    LOAD_HALF(A0, ws + WOFF);            // prefetch: stays in flight through L0
    h8 pe0 = *(const h8*)&X[xrow0 + g * 8];
    h8 pe1 = *(const h8*)&X[xrow1 + g * 8];
#pragma unroll
    for (int nt = 0; nt < 8; ++nt) {
      f4 bini = *(const f4*)&BL[nt * 16 + 4 * g];
      f4 acc0 = MFMA16(Av[nt], pe0, bini, 0, 0, 0);
      f4 acc1 = MFMA16(Av[nt], pe1, bini, 0, 0, 0);
      const int col = nt * 16 + 4 * g;   // no relu on vde output
      *(uint2*)&X[xrow0 + col] = make_uint2(
        (u32)f2h(acc0[0]) | ((u32)f2h(acc0[1]) << 16),
        (u32)f2h(acc0[2]) | ((u32)f2h(acc0[3]) << 16));
      *(uint2*)&X[xrow1 + col] = make_uint2(
        (u32)f2h(acc1[0]) | ((u32)f2h(acc1[1]) << 16),
        (u32)f2h(acc1[2]) | ((u32)f2h(acc1[3]) << 16));
    }
  }

  // ---- 11 full 128x128 layers: li 0..2 = vh MLP, 3..8 = hidden, 9..10 = head
  u32 vhp[2][8][2];   // captured vh: set at li==2, used at li==5
#pragma unroll 1
  for (int li = 0; li < 11; ++li) {
    const u16* wl  = ws + WOFF + li * FULL;
    const int  blb = (li + 1) * 128;                     // bias row in BL
    const int  mode = (li == 2) ? 1 : (li == 5) ? 2 : 0; // 1=capture, 2=modulate

    LOAD_HALF(A1, wl + 64 * RS);         // issue H1 while prefetched H0 lands

    h8 x0[4], x1[4];                     // activations read once -> X writable
#pragma unroll
    for (int ks = 0; ks < 4; ++ks) {
      x0[ks] = *(const h8*)&X[xrow0 + ks * 32 + g * 8];
      x1[ks] = *(const h8*)&X[xrow1 + ks * 32 + g * 8];
    }

    COMPUTE_HALF(0, A0);                 // waits vmcnt(16): H1 stays in flight

    LOAD_HALF(A0, wl + FULL);            // prefetch next layer's H0 (li=10 -> head tile)

    COMPUTE_HALF(1, A1);                 // waits vmcnt(16): next-H0 in flight

    // ---- after vh capture: embedding gather + renorm + bary -> X
    if (li == 2) {
#pragma unroll 2
      for (int i = 0; i < 8; ++i) {
        int p = pb + g * 8 + i;                // 16-lane group g handles 8 pixels
        size_t gp = bpix + p;
        const int*   vi = vert + gp * 3;
        const float* by = bary + gp * 3;
        f4 va = {0.f,0.f,0.f,0.f}, vb = {0.f,0.f,0.f,0.f};
#pragma unroll
        for (int vt = 0; vt < 3; ++vt) {
          int id = vi[vt] + 1;
          const float* row = emb + (size_t)id * 128 + r * 8;  // lane r: 8 chans
          f4 e0 = *(const f4*)row;
          f4 e1 = *(const f4*)(row + 4);
          float ss = e0[0]*e0[0] + e0[1]*e0[1] + e0[2]*e0[2] + e0[3]*e0[3]
                   + e1[0]*e1[0] + e1[1]*e1[1] + e1[2]*e1[2] + e1[3]*e1[3];
          ss += __shfl_xor(ss, 1);             // reduce within the 16-lane group
          ss += __shfl_xor(ss, 2);
          ss += __shfl_xor(ss, 4);
          ss += __shfl_xor(ss, 8);
          float nrm = sqrtf(ss);
          float sc  = (nrm > 1.f) ? (1.f / (nrm + 1e-7f)) : 1.f;  // torch max_norm
          float wt  = by[vt] * sc;
#pragma unroll
          for (int j = 0; j < 4; ++j) { va[j] += wt * e0[j]; vb[j] += wt * e1[j]; }
        }
        h8 o;
#pragma unroll
        for (int j = 0; j < 4; ++j) { o[j] = (_Float16)va[j]; o[j+4] = (_Float16)vb[j]; }
        *(h8*)&X[p * RS + r * 8] = o;
      }
    }
    __builtin_amdgcn_s_barrier();   // scheduling hint: keep waves layer-aligned for L1
  }

  // ---- head_W2 (128 -> 4): consumes prefetched A0[0][*] (head tile rows 0..15)
  {
    h8 x0[4], x1[4];
#pragma unroll
    for (int ks = 0; ks < 4; ++ks) {
      x0[ks] = *(const h8*)&X[xrow0 + ks * 32 + g * 8];
      x1[ks] = *(const h8*)&X[xrow1 + ks * 32 + g * 8];
    }
    f4 b2 = *(const f4*)&BL[1536 + 4 * g];   // g==0 lanes: real head_b2
    f4 acc0 = b2, acc1 = b2;
#pragma unroll
    for (int ks = 0; ks < 4; ++ks) {
      acc0 = MFMA16(A0[0][ks], x0[ks], acc0, 0, 0, 0);
      acc1 = MFMA16(A0[0][ks], x1[ks], acc1, 0, 0, 0);
    }
    if (g == 0) {                      // lane r holds pixel r's rgba contiguously
      *(f4*)&out[(bpix + pb +      r) * 4] = acc0;
      *(f4*)&out[(bpix + pb + 16 + r) * 4] = acc1;
    }
  }
}

// ---------------------------------------------------------------------------
extern "C" void kernel_launch(void* const* d_in, const int* in_sizes, int n_in,
                              void* d_out, int out_size, void* d_ws, size_t ws_size,
                              hipStream_t stream) {
  const int*   vert    = (const int*)  d_in[0];
  const float* bary    = (const float*)d_in[1];
  const float* view    = (const float*)d_in[2];
  const float* emb     = (const float*)d_in[3];
  const float* vde_W   = (const float*)d_in[4];
  const float* vde_b   = (const float*)d_in[5];
  const float* vh_W    = (const float*)d_in[6];
  const float* vh_b    = (const float*)d_in[7];
  const float* hid_W   = (const float*)d_in[8];
  const float* hid_b   = (const float*)d_in[9];
  const float* head_W0 = (const float*)d_in[10];
  const float* head_b0 = (const float*)d_in[11];
  const float* head_W1 = (const float*)d_in[12];
  const float* head_b1 = (const float*)d_in[13];
  const float* head_W2 = (const float*)d_in[14];
  const float* head_b2 = (const float*)d_in[15];
  u16* wsp = (u16*)d_ws;   // needs 428032 B

  rc_prep<<<836, 256, 0, stream>>>(vde_W, vh_W, hid_W, head_W0, head_W1, head_W2, wsp);
  rc_main<<<4096, 256, 0, stream>>>(vert, bary, view, emb, vde_b, vh_b, hid_b,
                                    head_b0, head_b1, head_b2, wsp, (float*)d_out);
}

// Round 5
// 435.658 us; speedup vs baseline: 1.3223x; 1.3223x over previous
//
#include <hip/hip_runtime.h>

typedef unsigned int  u32;
typedef unsigned long long u64;
typedef unsigned short u16;
typedef __attribute__((ext_vector_type(8))) _Float16 h8;   // MFMA A/B frag: 8 fp16 = 4 VGPR
typedef __attribute__((ext_vector_type(4))) float    f4;   // MFMA C/D frag

#define RS    136    // padded row stride (fp16): 272B rows, 16B-aligned
#define PRS   40     // row stride for vde weights (K=18 padded to 32, stored 40)
#define PIXB  128    // pixels per block (4 waves x 32 pixels)
#define WOFF  5120   // vde region size (halves)
#define FULL  17408  // 128*RS: one full layer tile (halves)
#define MFMA16 __builtin_amdgcn_mfma_f32_16x16x32_f16

__device__ __forceinline__ u16 f2h(float f) {
  _Float16 h = (_Float16)f;
  return __builtin_bit_cast(u16, h);
}
__device__ __forceinline__ float h2f(u16 u) {
  return (float)__builtin_bit_cast(_Float16, u);
}

// ---------------------------------------------------------------------------
// Prep: fp16 weights, transposed to [out][in], padded rows.
// ws layout (fp16 elems): [0, 5120)       vdeT [128][40] (k<18 valid)
//   [5120 + j*17408), j=0..11 : 12 x [128][136]
//   j: 0..2 vh, 3..8 hid, 9 headW0, 10 headW1, 11 headW2 (n>=4 zero)
// ---------------------------------------------------------------------------
__global__ __launch_bounds__(256) void rc_prep(
    const float* __restrict__ vde_W, const float* __restrict__ vh_W,
    const float* __restrict__ hid_W, const float* __restrict__ head_W0,
    const float* __restrict__ head_W1, const float* __restrict__ head_W2,
    u16* __restrict__ ws)
{
  const int TOT = WOFF + 12 * FULL;   // 214016
  int i = blockIdx.x * 256 + threadIdx.x;
  if (i >= TOT) return;
  float val = 0.f;
  if (i < WOFF) {
    int n = i / PRS, k = i - n * PRS;
    if (k < 18) val = vde_W[k * 128 + n];
  } else {
    int t = i - WOFF;
    int j = t / FULL;
    int rr = t - j * FULL;
    int n = rr / RS, k = rr - n * RS;
    if (k < 128) {
      if (j < 3)        val = vh_W[j * 16384 + k * 128 + n];
      else if (j < 9)   val = hid_W[(j - 3) * 16384 + k * 128 + n];
      else if (j == 9)  val = head_W0[k * 128 + n];
      else if (j == 10) val = head_W1[k * 128 + n];
      else              val = (n < 4) ? head_W2[k * 4 + n] : 0.f;
    }
  }
  ws[i] = f2h(val);
}

// ---------------------------------------------------------------------------
// Inline-asm weight loads: the compiler cannot sink/reorder these, and no
// automatic s_waitcnt is emitted for them — counted waits below are ours.
// ---------------------------------------------------------------------------
#define GLOAD(dst, base, voff, immstr)                                        \
  asm volatile("global_load_dwordx4 %0, %1, %2 offset:" immstr               \
               : "=v"(dst) : "v"(voff), "s"(base) : "memory")

// issue the 4 ks-frags of output-tile NT into ring slot S (64B per lane)
#define ISSUE(S, NT) do {                                                     \
  u32 vo_ = aoff + (NT) * 4352;   /* 16 rows * 272 B */                       \
  GLOAD(Ar##S[0], wbase, vo_, "0");                                           \
  GLOAD(Ar##S[1], wbase, vo_, "64");                                          \
  GLOAD(Ar##S[2], wbase, vo_, "128");                                         \
  GLOAD(Ar##S[3], wbase, vo_, "192");                                         \
} while (0)

// counted wait + scheduling fence (rule #18: MFMA must not hoist above it)
#define WAITV(nstr) do {                                                      \
  asm volatile("s_waitcnt vmcnt(" nstr ")" ::: "memory");                     \
  __builtin_amdgcn_sched_barrier(0);                                          \
} while (0)

// compute output-tile NT from ring slot S: bias-init (LDS), 8 MFMA,
// relu + mode handling, packed ds_write_b64 epilogue
#define COMPUTE_NT(S, NT) do {                                                \
  f4 bini = *(const f4*)&BL[blb + (NT) * 16 + 4 * g];                         \
  f4 acc0 = bini, acc1 = bini;                                                \
  _Pragma("unroll")                                                           \
  for (int ks = 0; ks < 4; ++ks) {                                            \
    acc0 = MFMA16(Ar##S[ks], x0[ks], acc0, 0, 0, 0);                          \
    acc1 = MFMA16(Ar##S[ks], x1[ks], acc1, 0, 0, 0);                          \
  }                                                                           \
  float v00 = fmaxf(acc0[0], 0.f), v01 = fmaxf(acc0[1], 0.f);                 \
  float v02 = fmaxf(acc0[2], 0.f), v03 = fmaxf(acc0[3], 0.f);                 \
  float v10 = fmaxf(acc1[0], 0.f), v11 = fmaxf(acc1[1], 0.f);                 \
  float v12 = fmaxf(acc1[2], 0.f), v13 = fmaxf(acc1[3], 0.f);                 \
  if (mode == 1) {                       /* capture vh in regs */             \
    vhp[0][NT][0] = (u32)f2h(v00) | ((u32)f2h(v01) << 16);                    \
    vhp[0][NT][1] = (u32)f2h(v02) | ((u32)f2h(v03) << 16);                    \
    vhp[1][NT][0] = (u32)f2h(v10) | ((u32)f2h(v11) << 16);                    \
    vhp[1][NT][1] = (u32)f2h(v12) | ((u32)f2h(v13) << 16);                    \
  } else {                                                                    \
    if (mode == 2) {                     /* h = relu(out) * vh */             \
      v00 *= h2f((u16)(vhp[0][NT][0] & 0xffffu));                             \
      v01 *= h2f((u16)(vhp[0][NT][0] >> 16));                                 \
      v02 *= h2f((u16)(vhp[0][NT][1] & 0xffffu));                             \
      v03 *= h2f((u16)(vhp[0][NT][1] >> 16));                                 \
      v10 *= h2f((u16)(vhp[1][NT][0] & 0xffffu));                             \
      v11 *= h2f((u16)(vhp[1][NT][0] >> 16));                                 \
      v12 *= h2f((u16)(vhp[1][NT][1] & 0xffffu));                             \
      v13 *= h2f((u16)(vhp[1][NT][1] >> 16));                                 \
    }                                                                         \
    const int col = (NT) * 16 + 4 * g;                                        \
    *(uint2*)&X[xrow0 + col] = make_uint2(                                    \
      (u32)f2h(v00) | ((u32)f2h(v01) << 16),                                  \
      (u32)f2h(v02) | ((u32)f2h(v03) << 16));                                 \
    *(uint2*)&X[xrow1 + col] = make_uint2(                                    \
      (u32)f2h(v10) | ((u32)f2h(v11) << 16),                                  \
      (u32)f2h(v12) | ((u32)f2h(v13) << 16));                                 \
  }                                                                           \
} while (0)

// ---------------------------------------------------------------------------
// Main fused kernel — R2 structure + asm-forced distance-2 prefetch ring.
// Steady state: 8 weight loads (2 nt-steps) in flight; vmcnt(8) waits only
// for the current step's frags. Loop body is vmem-clean (biases in LDS).
// ---------------------------------------------------------------------------
__global__ __launch_bounds__(256, 3) void rc_main(
    const int*   __restrict__ vert,  const float* __restrict__ bary,
    const float* __restrict__ view,  const float* __restrict__ emb,
    const float* __restrict__ vde_b, const float* __restrict__ vh_b,
    const float* __restrict__ hid_b, const float* __restrict__ head_b0,
    const float* __restrict__ head_b1, const float* __restrict__ head_b2,
    const u16*   __restrict__ ws,    float* __restrict__ out)
{
  __shared__ __align__(16) u16   X[PIXB * RS];   // 34816 B activations
  __shared__ __align__(16) float BL[1664];       // 6656 B: all biases

  const int tid  = threadIdx.x;
  const int lane = tid & 63;
  const int w    = tid >> 6;
  const int r    = lane & 15;       // pixel-within-tile (B col / D col); A row
  const int g    = lane >> 4;       // k-group; D row group
  const int pb   = w * 32;          // wave's first pixel row
  const size_t bpix = (size_t)blockIdx.x * PIXB;

  // ---- cooperative bias load into LDS
  for (int i = tid; i < 1664; i += 256) {
    float v;
    if      (i < 128)  v = vde_b[i];
    else if (i < 512)  v = vh_b[i - 128];
    else if (i < 1280) v = hid_b[i - 512];
    else if (i < 1408) v = head_b0[i - 1280];
    else if (i < 1536) v = head_b1[i - 1408];
    else if (i < 1540) v = head_b2[i - 1536];
    else               v = 0.f;
    BL[i] = v;
  }

  // ---- PE: lanes 0..31 compute their pixel's sin/cos encoding into X[row][0..32)
  if (lane < 32) {
    const int p = pb + lane;
    const float* vd = view + (bpix + p) * 3;
    const float SG0 = 6.28318530718f;   // 2pi / 0.9^0
    const float SG1 = 6.50777324f;      // 2pi / 0.9^(1/3)
    const float SG2 = 6.74038866f;      // 2pi / 0.9^(2/3)
    u32 pw[16];
#pragma unroll
    for (int i = 0; i < 3; ++i) {
      float x = vd[i];
      float s0 = __sinf(x * SG0), c0 = __cosf(x * SG0);
      float s1 = __sinf(x * SG1), c1 = __cosf(x * SG1);
      float s2 = __sinf(x * SG2), c2 = __cosf(x * SG2);
      pw[i * 3 + 0] = (u32)f2h(s0) | ((u32)f2h(s1) << 16);
      pw[i * 3 + 1] = (u32)f2h(s2) | ((u32)f2h(c0) << 16);
      pw[i * 3 + 2] = (u32)f2h(c1) | ((u32)f2h(c2) << 16);
    }
#pragma unroll
    for (int q = 9; q < 16; ++q) pw[q] = 0u;   // zero-pad k = 18..31
    uint4* dst = (uint4*)&X[p * RS];
#pragma unroll
    for (int q = 0; q < 4; ++q)
      dst[q] = make_uint4(pw[4*q], pw[4*q+1], pw[4*q+2], pw[4*q+3]);
  }
  __syncthreads();   // once; everything below is wave-private in X

  const int xrow0 = (pb +      r) * RS;
  const int xrow1 = (pb + 16 + r) * RS;
  const u32 aoff  = (u32)(r * RS + g * 8) * 2;   // per-lane A-frag byte offset

  // ---- L0: vde (K=18 padded to 32) — small, compiler-scheduled loads
  {
    h8 Av[8];
#pragma unroll
    for (int nt = 0; nt < 8; ++nt)
      Av[nt] = *(const h8*)&ws[(nt * 16 + r) * PRS + g * 8];
    h8 pe0 = *(const h8*)&X[xrow0 + g * 8];
    h8 pe1 = *(const h8*)&X[xrow1 + g * 8];
#pragma unroll
    for (int nt = 0; nt < 8; ++nt) {
      f4 bini = *(const f4*)&BL[nt * 16 + 4 * g];
      f4 acc0 = MFMA16(Av[nt], pe0, bini, 0, 0, 0);
      f4 acc1 = MFMA16(Av[nt], pe1, bini, 0, 0, 0);
      const int col = nt * 16 + 4 * g;   // no relu on vde output
      *(uint2*)&X[xrow0 + col] = make_uint2(
        (u32)f2h(acc0[0]) | ((u32)f2h(acc0[1]) << 16),
        (u32)f2h(acc0[2]) | ((u32)f2h(acc0[3]) << 16));
      *(uint2*)&X[xrow1 + col] = make_uint2(
        (u32)f2h(acc1[0]) | ((u32)f2h(acc1[1]) << 16),
        (u32)f2h(acc1[2]) | ((u32)f2h(acc1[3]) << 16));
    }
  }

  // ---- 11 full 128x128 layers: li 0..2 = vh MLP, 3..8 = hidden, 9..10 = head
  u32 vhp[2][8][2];   // captured vh: set at li==2, used at li==5
  h8 Ar0[4], Ar1[4], Ar2[4];   // 3-slot prefetch ring (48 VGPRs)
#pragma unroll 1
  for (int li = 0; li < 11; ++li) {
    const u64 wbase = (u64)(uintptr_t)(ws + WOFF + li * FULL);
    const int blb   = (li + 1) * 128;                     // bias row in BL
    const int mode  = (li == 2) ? 1 : (li == 5) ? 2 : 0;  // 1=capture, 2=modulate

    ISSUE(0, 0);
    ISSUE(1, 1);

    h8 x0[4], x1[4];                     // activations read once -> X writable
#pragma unroll
    for (int ks = 0; ks < 4; ++ks) {
      x0[ks] = *(const h8*)&X[xrow0 + ks * 32 + g * 8];
      x1[ks] = *(const h8*)&X[xrow1 + ks * 32 + g * 8];
    }

    ISSUE(2, 2);  WAITV("8");  COMPUTE_NT(0, 0);
    ISSUE(0, 3);  WAITV("8");  COMPUTE_NT(1, 1);
    ISSUE(1, 4);  WAITV("8");  COMPUTE_NT(2, 2);
    ISSUE(2, 5);  WAITV("8");  COMPUTE_NT(0, 3);
    ISSUE(0, 6);  WAITV("8");  COMPUTE_NT(1, 4);
    ISSUE(1, 7);  WAITV("8");  COMPUTE_NT(2, 5);
                  WAITV("4");  COMPUTE_NT(0, 6);
                  WAITV("0");  COMPUTE_NT(1, 7);

    // ---- after vh capture: embedding gather + renorm + bary -> X (vmcnt==0 here)
    if (li == 2) {
#pragma unroll 2
      for (int i = 0; i < 8; ++i) {
        int p = pb + g * 8 + i;                // 16-lane group g handles 8 pixels
        size_t gp = bpix + p;
        const int*   vi = vert + gp * 3;
        const float* by = bary + gp * 3;
        f4 va = {0.f,0.f,0.f,0.f}, vb = {0.f,0.f,0.f,0.f};
#pragma unroll
        for (int vt = 0; vt < 3; ++vt) {
          int id = vi[vt] + 1;
          const float* row = emb + (size_t)id * 128 + r * 8;  // lane r: 8 chans
          f4 e0 = *(const f4*)row;
          f4 e1 = *(const f4*)(row + 4);
          float ss = e0[0]*e0[0] + e0[1]*e0[1] + e0[2]*e0[2] + e0[3]*e0[3]
                   + e1[0]*e1[0] + e1[1]*e1[1] + e1[2]*e1[2] + e1[3]*e1[3];
          ss += __shfl_xor(ss, 1);             // reduce within the 16-lane group
          ss += __shfl_xor(ss, 2);
          ss += __shfl_xor(ss, 4);
          ss += __shfl_xor(ss, 8);
          float nrm = sqrtf(ss);
          float sc  = (nrm > 1.f) ? (1.f / (nrm + 1e-7f)) : 1.f;  // torch max_norm
          float wt  = by[vt] * sc;
#pragma unroll
          for (int j = 0; j < 4; ++j) { va[j] += wt * e0[j]; vb[j] += wt * e1[j]; }
        }
        h8 o;
#pragma unroll
        for (int j = 0; j < 4; ++j) { o[j] = (_Float16)va[j]; o[j+4] = (_Float16)vb[j]; }
        *(h8*)&X[p * RS + r * 8] = o;
      }
    }
    __builtin_amdgcn_s_barrier();   // keep block's waves layer-aligned for L1 reuse
  }

  // ---- head_W2 (128 -> 4) + head_b2, compiler-scheduled (tail, negligible)
  {
    h8 x0[4], x1[4];
#pragma unroll
    for (int ks = 0; ks < 4; ++ks) {
      x0[ks] = *(const h8*)&X[xrow0 + ks * 32 + g * 8];
      x1[ks] = *(const h8*)&X[xrow1 + ks * 32 + g * 8];
    }
    const u16* wa = ws + WOFF + 11 * FULL;
    f4 b2 = *(const f4*)&BL[1536 + 4 * g];   // g==0 lanes: real head_b2
    f4 acc0 = b2, acc1 = b2;
#pragma unroll
    for (int ks = 0; ks < 4; ++ks) {
      h8 A = *(const h8*)&wa[r * RS + ks * 32 + g * 8];
      acc0 = MFMA16(A, x0[ks], acc0, 0, 0, 0);
      acc1 = MFMA16(A, x1[ks], acc1, 0, 0, 0);
    }
    if (g == 0) {                      // lane r holds pixel r's rgba contiguously
      *(f4*)&out[(bpix + pb +      r) * 4] = acc0;
      *(f4*)&out[(bpix + pb + 16 + r) * 4] = acc1;
    }
  }
}

// ---------------------------------------------------------------------------
extern "C" void kernel_launch(void* const* d_in, const int* in_sizes, int n_in,
                              void* d_out, int out_size, void* d_ws, size_t ws_size,
                              hipStream_t stream) {
  const int*   vert    = (const int*)  d_in[0];
  const float* bary    = (const float*)d_in[1];
  const float* view    = (const float*)d_in[2];
  const float* emb     = (const float*)d_in[3];
  const float* vde_W   = (const float*)d_in[4];
  const float* vde_b   = (const float*)d_in[5];
  const float* vh_W    = (const float*)d_in[6];
  const float* vh_b    = (const float*)d_in[7];
  const float* hid_W   = (const float*)d_in[8];
  const float* hid_b   = (const float*)d_in[9];
  const float* head_W0 = (const float*)d_in[10];
  const float* head_b0 = (const float*)d_in[11];
  const float* head_W1 = (const float*)d_in[12];
  const float* head_b1 = (const float*)d_in[13];
  const float* head_W2 = (const float*)d_in[14];
  const float* head_b2 = (const float*)d_in[15];
  u16* wsp = (u16*)d_ws;   // needs 428032 B

  rc_prep<<<836, 256, 0, stream>>>(vde_W, vh_W, hid_W, head_W0, head_W1, head_W2, wsp);
  rc_main<<<4096, 256, 0, stream>>>(vert, bary, view, emb, vde_b, vh_b, hid_b,
                                    head_b0, head_b1, head_b2, wsp, (float*)d_out);
}

// Round 6
// 376.548 us; speedup vs baseline: 1.5299x; 1.1570x over previous
//
#include <hip/hip_runtime.h>

typedef unsigned int  u32;
typedef unsigned long long u64;
typedef unsigned short u16;
typedef __attribute__((ext_vector_type(8))) _Float16 h8;   // MFMA A/B frag: 8 fp16 = 4 VGPR
typedef __attribute__((ext_vector_type(2))) _Float16 h2;   // packed fp16 pair
typedef __attribute__((ext_vector_type(4))) float    f4;   // MFMA C/D frag

#define RS    136    // padded row stride (fp16): 272B rows, 16B-aligned
#define PRS   40     // row stride for vde weights (K=18 padded to 32, stored 40)
#define PIXB  256    // pixels per block (4 waves x 64 pixels)
#define WOFF  5120   // vde region size (halves)
#define FULL  17408  // 128*RS: one full layer tile (halves)
#define MFMA16 __builtin_amdgcn_mfma_f32_16x16x32_f16

__device__ __forceinline__ u16 f2h(float f) {
  _Float16 h = (_Float16)f;
  return __builtin_bit_cast(u16, h);
}
__device__ __forceinline__ u32 pkrtz(float a, float b) {
  return __builtin_bit_cast(u32, __builtin_amdgcn_cvt_pkrtz(a, b));
}
__device__ __forceinline__ u32 pkmul(u32 a, u32 b) {   // v_pk_mul_f16
  h2 r = __builtin_bit_cast(h2, a) * __builtin_bit_cast(h2, b);
  return __builtin_bit_cast(u32, r);
}

// ---------------------------------------------------------------------------
// Prep: fp16 weights, transposed to [out][in], padded rows.
// ws layout (fp16 elems): [0, 5120)       vdeT [128][40] (k<18 valid)
//   [5120 + j*17408), j=0..11 : 12 x [128][136]
//   j: 0..2 vh, 3..8 hid, 9 headW0, 10 headW1, 11 headW2 (n>=4 zero)
// ---------------------------------------------------------------------------
__global__ __launch_bounds__(256) void rc_prep(
    const float* __restrict__ vde_W, const float* __restrict__ vh_W,
    const float* __restrict__ hid_W, const float* __restrict__ head_W0,
    const float* __restrict__ head_W1, const float* __restrict__ head_W2,
    u16* __restrict__ ws)
{
  const int TOT = WOFF + 12 * FULL;   // 214016
  int i = blockIdx.x * 256 + threadIdx.x;
  if (i >= TOT) return;
  float val = 0.f;
  if (i < WOFF) {
    int n = i / PRS, k = i - n * PRS;
    if (k < 18) val = vde_W[k * 128 + n];
  } else {
    int t = i - WOFF;
    int j = t / FULL;
    int rr = t - j * FULL;
    int n = rr / RS, k = rr - n * RS;
    if (k < 128) {
      if (j < 3)        val = vh_W[j * 16384 + k * 128 + n];
      else if (j < 9)   val = hid_W[(j - 3) * 16384 + k * 128 + n];
      else if (j == 9)  val = head_W0[k * 128 + n];
      else if (j == 10) val = head_W1[k * 128 + n];
      else              val = (n < 4) ? head_W2[k * 4 + n] : 0.f;
    }
  }
  ws[i] = f2h(val);
}

// ---------------------------------------------------------------------------
// Inline-asm weight loads (compiler cannot sink/reorder; waits are ours).
// ---------------------------------------------------------------------------
#define GLOAD(dst, base, voff, immstr)                                        \
  asm volatile("global_load_dwordx4 %0, %1, %2 offset:" immstr               \
               : "=v"(dst) : "v"(voff), "s"(base) : "memory")

#define ISSUE(S, NT) do {                                                     \
  u32 vo_ = aoff + (NT) * 4352;   /* 16 rows * 272 B */                       \
  GLOAD(Ar##S[0], wbase, vo_, "0");                                           \
  GLOAD(Ar##S[1], wbase, vo_, "64");                                          \
  GLOAD(Ar##S[2], wbase, vo_, "128");                                         \
  GLOAD(Ar##S[3], wbase, vo_, "192");                                         \
} while (0)

#define WAITV(nstr) do {                                                      \
  asm volatile("s_waitcnt vmcnt(" nstr ")" ::: "memory");                     \
  __builtin_amdgcn_sched_barrier(0);                                          \
} while (0)

// compute output-tile NT (all 4 pixel-tiles) from ring slot S.
// epilogue: relu (f32 fmax) -> cvt_pkrtz -> [capture | pk_mul modulate] ->
// one ds_write_b64 per pixel-tile. Bias folded into MFMA C-init.
#define COMPUTE_NT(S, NT) do {                                                \
  f4 bini = *(const f4*)&BL[blb + (NT) * 16 + 4 * g];                         \
  f4 ac[4] = {bini, bini, bini, bini};                                        \
  _Pragma("unroll")                                                           \
  for (int ks = 0; ks < 4; ++ks) {                                            \
    ac[0] = MFMA16(Ar##S[ks], x[0][ks], ac[0], 0, 0, 0);                      \
    ac[1] = MFMA16(Ar##S[ks], x[1][ks], ac[1], 0, 0, 0);                      \
    ac[2] = MFMA16(Ar##S[ks], x[2][ks], ac[2], 0, 0, 0);                      \
    ac[3] = MFMA16(Ar##S[ks], x[3][ks], ac[3], 0, 0, 0);                      \
  }                                                                           \
  const int col = (NT) * 16 + 4 * g;                                          \
  _Pragma("unroll")                                                           \
  for (int t = 0; t < 4; ++t) {                                               \
    u32 lo = pkrtz(fmaxf(ac[t][0], 0.f), fmaxf(ac[t][1], 0.f));               \
    u32 hi = pkrtz(fmaxf(ac[t][2], 0.f), fmaxf(ac[t][3], 0.f));               \
    if (mode == 1) {                       /* capture vh (already packed) */  \
      vhp[t][NT][0] = lo; vhp[t][NT][1] = hi;                                 \
    } else {                                                                  \
      if (mode == 2) {                     /* h = relu(out) * vh, packed */   \
        lo = pkmul(lo, vhp[t][NT][0]);                                        \
        hi = pkmul(hi, vhp[t][NT][1]);                                        \
      }                                                                       \
      *(uint2*)&X[xr[t] + col] = make_uint2(lo, hi);                          \
    }                                                                         \
  }                                                                           \
} while (0)

// ---------------------------------------------------------------------------
// Main fused kernel — 64 pixels/wave (4 pixel-tiles), asm distance-1 ring.
// Per nt-step: 4 weight loads feed 16 MFMA (4x compute per byte vs R5).
// X rows wave-private; loop body vmem-clean (biases in LDS).
// ---------------------------------------------------------------------------
__global__ __launch_bounds__(256, 2) void rc_main(
    const int*   __restrict__ vert,  const float* __restrict__ bary,
    const float* __restrict__ view,  const float* __restrict__ emb,
    const float* __restrict__ vde_b, const float* __restrict__ vh_b,
    const float* __restrict__ hid_b, const float* __restrict__ head_b0,
    const float* __restrict__ head_b1, const float* __restrict__ head_b2,
    const u16*   __restrict__ ws,    float* __restrict__ out)
{
  __shared__ __align__(16) u16   X[PIXB * RS];   // 69632 B activations
  __shared__ __align__(16) float BL[1664];       // 6656 B: all biases

  const int tid  = threadIdx.x;
  const int lane = tid & 63;
  const int w    = tid >> 6;
  const int r    = lane & 15;       // pixel-within-tile (B col / D col); A row
  const int g    = lane >> 4;       // k-group; D row group
  const int pb   = w * 64;          // wave's first pixel row (64 px/wave)
  const size_t bpix = (size_t)blockIdx.x * PIXB;

  // ---- cooperative bias load into LDS
  for (int i = tid; i < 1664; i += 256) {
    float v;
    if      (i < 128)  v = vde_b[i];
    else if (i < 512)  v = vh_b[i - 128];
    else if (i < 1280) v = hid_b[i - 512];
    else if (i < 1408) v = head_b0[i - 1280];
    else if (i < 1536) v = head_b1[i - 1408];
    else if (i < 1540) v = head_b2[i - 1536];
    else               v = 0.f;
    BL[i] = v;
  }

  // ---- PE: every lane computes its pixel's sin/cos encoding into X[row][0..32)
  {
    const int p = pb + lane;
    const float* vd = view + (bpix + p) * 3;
    const float SG0 = 6.28318530718f;   // 2pi / 0.9^0
    const float SG1 = 6.50777324f;      // 2pi / 0.9^(1/3)
    const float SG2 = 6.74038866f;      // 2pi / 0.9^(2/3)
    u32 pw[16];
#pragma unroll
    for (int i = 0; i < 3; ++i) {
      float x = vd[i];
      float s0 = __sinf(x * SG0), c0 = __cosf(x * SG0);
      float s1 = __sinf(x * SG1), c1 = __cosf(x * SG1);
      float s2 = __sinf(x * SG2), c2 = __cosf(x * SG2);
      pw[i * 3 + 0] = (u32)f2h(s0) | ((u32)f2h(s1) << 16);
      pw[i * 3 + 1] = (u32)f2h(s2) | ((u32)f2h(c0) << 16);
      pw[i * 3 + 2] = (u32)f2h(c1) | ((u32)f2h(c2) << 16);
    }
#pragma unroll
    for (int q = 9; q < 16; ++q) pw[q] = 0u;   // zero-pad k = 18..31
    uint4* dst = (uint4*)&X[p * RS];
#pragma unroll
    for (int q = 0; q < 4; ++q)
      dst[q] = make_uint4(pw[4*q], pw[4*q+1], pw[4*q+2], pw[4*q+3]);
  }
  __syncthreads();   // once; everything below is wave-private in X

  const int xr[4] = { (pb +      r) * RS, (pb + 16 + r) * RS,
                      (pb + 32 + r) * RS, (pb + 48 + r) * RS };
  const u32 aoff  = (u32)(r * RS + g * 8) * 2;   // per-lane A-frag byte offset

  // ---- L0: vde (K=18 padded to 32) — small, compiler-scheduled loads
  {
    h8 Av[8];
#pragma unroll
    for (int nt = 0; nt < 8; ++nt)
      Av[nt] = *(const h8*)&ws[(nt * 16 + r) * PRS + g * 8];
    h8 pe[4];
#pragma unroll
    for (int t = 0; t < 4; ++t) pe[t] = *(const h8*)&X[xr[t] + g * 8];
#pragma unroll
    for (int nt = 0; nt < 8; ++nt) {
      f4 bini = *(const f4*)&BL[nt * 16 + 4 * g];
      const int col = nt * 16 + 4 * g;
#pragma unroll
      for (int t = 0; t < 4; ++t) {
        f4 acc = MFMA16(Av[nt], pe[t], bini, 0, 0, 0);
        *(uint2*)&X[xr[t] + col] =          // no relu on vde output
          make_uint2(pkrtz(acc[0], acc[1]), pkrtz(acc[2], acc[3]));
      }
    }
  }

  // ---- 11 full 128x128 layers: li 0..2 = vh MLP, 3..8 = hidden, 9..10 = head
  u32 vhp[4][8][2];            // captured vh: set at li==2, used at li==5
  h8 Ar0[4], Ar1[4];           // 2-slot prefetch ring (32 VGPRs)
#pragma unroll 1
  for (int li = 0; li < 11; ++li) {
    const u64 wbase = (u64)(uintptr_t)(ws + WOFF + li * FULL);
    const int blb   = (li + 1) * 128;                     // bias row in BL
    const int mode  = (li == 2) ? 1 : (li == 5) ? 2 : 0;  // 1=capture, 2=modulate

    ISSUE(0, 0);
    ISSUE(1, 1);

    h8 x[4][4];                          // activations read once -> X writable
#pragma unroll
    for (int t = 0; t < 4; ++t)
#pragma unroll
      for (int ks = 0; ks < 4; ++ks)
        x[t][ks] = *(const h8*)&X[xr[t] + ks * 32 + g * 8];

    WAITV("4");  COMPUTE_NT(0, 0);  ISSUE(0, 2);
    WAITV("4");  COMPUTE_NT(1, 1);  ISSUE(1, 3);
    WAITV("4");  COMPUTE_NT(0, 2);  ISSUE(0, 4);
    WAITV("4");  COMPUTE_NT(1, 3);  ISSUE(1, 5);
    WAITV("4");  COMPUTE_NT(0, 4);  ISSUE(0, 6);
    WAITV("4");  COMPUTE_NT(1, 5);  ISSUE(1, 7);
    WAITV("4");  COMPUTE_NT(0, 6);
    WAITV("0");  COMPUTE_NT(1, 7);

    // ---- after vh capture: embedding gather + renorm + bary -> X (vmcnt==0 here)
    if (li == 2) {
#pragma unroll 2
      for (int i = 0; i < 16; ++i) {
        int p = pb + g * 16 + i;               // 16-lane group g handles 16 pixels
        size_t gp = bpix + p;
        const int*   vi = vert + gp * 3;
        const float* by = bary + gp * 3;
        f4 va = {0.f,0.f,0.f,0.f}, vb = {0.f,0.f,0.f,0.f};
#pragma unroll
        for (int vt = 0; vt < 3; ++vt) {
          int id = vi[vt] + 1;
          const float* row = emb + (size_t)id * 128 + r * 8;  // lane r: 8 chans
          f4 e0 = *(const f4*)row;
          f4 e1 = *(const f4*)(row + 4);
          float ss = e0[0]*e0[0] + e0[1]*e0[1] + e0[2]*e0[2] + e0[3]*e0[3]
                   + e1[0]*e1[0] + e1[1]*e1[1] + e1[2]*e1[2] + e1[3]*e1[3];
          ss += __shfl_xor(ss, 1);             // reduce within the 16-lane group
          ss += __shfl_xor(ss, 2);
          ss += __shfl_xor(ss, 4);
          ss += __shfl_xor(ss, 8);
          float nrm = sqrtf(ss);
          float sc  = (nrm > 1.f) ? (1.f / (nrm + 1e-7f)) : 1.f;  // torch max_norm
          float wt  = by[vt] * sc;
#pragma unroll
          for (int j = 0; j < 4; ++j) { va[j] += wt * e0[j]; vb[j] += wt * e1[j]; }
        }
        h8 o;
#pragma unroll
        for (int j = 0; j < 4; ++j) { o[j] = (_Float16)va[j]; o[j+4] = (_Float16)vb[j]; }
        *(h8*)&X[p * RS + r * 8] = o;
      }
    }
    __builtin_amdgcn_s_barrier();   // keep block's waves layer-aligned for L1 reuse
  }

  // ---- head_W2 (128 -> 4) + head_b2, compiler-scheduled (tail, negligible)
  {
    h8 x[4][4];
#pragma unroll
    for (int t = 0; t < 4; ++t)
#pragma unroll
      for (int ks = 0; ks < 4; ++ks)
        x[t][ks] = *(const h8*)&X[xr[t] + ks * 32 + g * 8];
    const u16* wa = ws + WOFF + 11 * FULL;
    f4 b2 = *(const f4*)&BL[1536 + 4 * g];   // g==0 lanes: real head_b2
    f4 acc[4] = {b2, b2, b2, b2};
#pragma unroll
    for (int ks = 0; ks < 4; ++ks) {
      h8 A = *(const h8*)&wa[r * RS + ks * 32 + g * 8];
#pragma unroll
      for (int t = 0; t < 4; ++t)
        acc[t] = MFMA16(A, x[t][ks], acc[t], 0, 0, 0);
    }
    if (g == 0) {                      // lane r holds pixel r's rgba contiguously
#pragma unroll
      for (int t = 0; t < 4; ++t)
        *(f4*)&out[(bpix + pb + t * 16 + r) * 4] = acc[t];
    }
  }
}

// ---------------------------------------------------------------------------
extern "C" void kernel_launch(void* const* d_in, const int* in_sizes, int n_in,
                              void* d_out, int out_size, void* d_ws, size_t ws_size,
                              hipStream_t stream) {
  const int*   vert    = (const int*)  d_in[0];
  const float* bary    = (const float*)d_in[1];
  const float* view    = (const float*)d_in[2];
  const float* emb     = (const float*)d_in[3];
  const float* vde_W   = (const float*)d_in[4];
  const float* vde_b   = (const float*)d_in[5];
  const float* vh_W    = (const float*)d_in[6];
  const float* vh_b    = (const float*)d_in[7];
  const float* hid_W   = (const float*)d_in[8];
  const float* hid_b   = (const float*)d_in[9];
  const float* head_W0 = (const float*)d_in[10];
  const float* head_b0 = (const float*)d_in[11];
  const float* head_W1 = (const float*)d_in[12];
  const float* head_b1 = (const float*)d_in[13];
  const float* head_W2 = (const float*)d_in[14];
  const float* head_b2 = (const float*)d_in[15];
  u16* wsp = (u16*)d_ws;   // needs 428032 B

  rc_prep<<<836, 256, 0, stream>>>(vde_W, vh_W, hid_W, head_W0, head_W1, head_W2, wsp);
  rc_main<<<2048, 256, 0, stream>>>(vert, bary, view, emb, vde_b, vh_b, hid_b,
                                    head_b0, head_b1, head_b2, wsp, (float*)d_out);
}

// Round 7
// 373.020 us; speedup vs baseline: 1.5443x; 1.0095x over previous
//
#include <hip/hip_runtime.h>

typedef unsigned int  u32;
typedef unsigned long long u64;
typedef unsigned short u16;
typedef __attribute__((ext_vector_type(8))) _Float16 h8;   // MFMA A/B frag: 8 fp16 = 4 VGPR
typedef __attribute__((ext_vector_type(2))) _Float16 h2;   // packed fp16 pair
typedef __attribute__((ext_vector_type(4))) float    f4;   // MFMA C/D frag

#define RS    136    // padded row stride (fp16): 272B rows, 16B-aligned
#define PRS   40     // row stride for vde weights (K=18 padded to 32, stored 40)
#define PIXB  256    // pixels per block (4 waves x 64 pixels)
#define WOFF  5120   // vde region size (halves)
#define FULL  17408  // 128*RS: one full layer tile (halves)
#define MFMA16 __builtin_amdgcn_mfma_f32_16x16x32_f16

__device__ __forceinline__ u16 f2h(float f) {
  _Float16 h = (_Float16)f;
  return __builtin_bit_cast(u16, h);
}
__device__ __forceinline__ u32 pkrtz(float a, float b) {
  return __builtin_bit_cast(u32, __builtin_amdgcn_cvt_pkrtz(a, b));
}
__device__ __forceinline__ u32 pkmul(u32 a, u32 b) {   // v_pk_mul_f16
  h2 r = __builtin_bit_cast(h2, a) * __builtin_bit_cast(h2, b);
  return __builtin_bit_cast(u32, r);
}
__device__ __forceinline__ u32 pkmax0(u32 a) {         // v_pk_max_f16 vs 0 (packed relu)
  h2 z = {(_Float16)0.f, (_Float16)0.f};
  h2 r = __builtin_elementwise_max(__builtin_bit_cast(h2, a), z);
  return __builtin_bit_cast(u32, r);
}

// ---------------------------------------------------------------------------
// Prep: fp16 weights, transposed to [out][in], padded rows.
// ws layout (fp16 elems): [0, 5120)       vdeT [128][40] (k<18 valid)
//   [5120 + j*17408), j=0..11 : 12 x [128][136]
//   j: 0..2 vh, 3..8 hid, 9 headW0, 10 headW1, 11 headW2 (n>=4 zero)
// ---------------------------------------------------------------------------
__global__ __launch_bounds__(256) void rc_prep(
    const float* __restrict__ vde_W, const float* __restrict__ vh_W,
    const float* __restrict__ hid_W, const float* __restrict__ head_W0,
    const float* __restrict__ head_W1, const float* __restrict__ head_W2,
    u16* __restrict__ ws)
{
  const int TOT = WOFF + 12 * FULL;   // 214016
  int i = blockIdx.x * 256 + threadIdx.x;
  if (i >= TOT) return;
  float val = 0.f;
  if (i < WOFF) {
    int n = i / PRS, k = i - n * PRS;
    if (k < 18) val = vde_W[k * 128 + n];
  } else {
    int t = i - WOFF;
    int j = t / FULL;
    int rr = t - j * FULL;
    int n = rr / RS, k = rr - n * RS;
    if (k < 128) {
      if (j < 3)        val = vh_W[j * 16384 + k * 128 + n];
      else if (j < 9)   val = hid_W[(j - 3) * 16384 + k * 128 + n];
      else if (j == 9)  val = head_W0[k * 128 + n];
      else if (j == 10) val = head_W1[k * 128 + n];
      else              val = (n < 4) ? head_W2[k * 4 + n] : 0.f;
    }
  }
  ws[i] = f2h(val);
}

// ---------------------------------------------------------------------------
// Inline-asm weight loads (compiler cannot sink/reorder; waits are ours).
// ---------------------------------------------------------------------------
#define GLOAD(dst, base, voff, immstr)                                        \
  asm volatile("global_load_dwordx4 %0, %1, %2 offset:" immstr               \
               : "=v"(dst) : "v"(voff), "s"(base) : "memory")

#define ISSUE(S, NT) do {                                                     \
  u32 vo_ = aoff + (NT) * 4352;   /* 16 rows * 272 B */                       \
  GLOAD(Ar##S[0], wbase, vo_, "0");                                           \
  GLOAD(Ar##S[1], wbase, vo_, "64");                                          \
  GLOAD(Ar##S[2], wbase, vo_, "128");                                         \
  GLOAD(Ar##S[3], wbase, vo_, "192");                                         \
} while (0)

#define WAITV(nstr) do {                                                      \
  asm volatile("s_waitcnt vmcnt(" nstr ")" ::: "memory");                     \
  __builtin_amdgcn_sched_barrier(0);                                          \
} while (0)

// compute output-tile NT (all 4 pixel-tiles) from ring slot S.
// epilogue: cvt_pkrtz -> v_pk_max_f16 (packed relu) ->
// [capture | pk_mul modulate] -> one ds_write_b64 per pixel-tile.
// Bias folded into MFMA C-init (exact f32).
#define COMPUTE_NT(S, NT) do {                                                \
  f4 bini = *(const f4*)&BL[blb + (NT) * 16 + 4 * g];                         \
  f4 ac[4] = {bini, bini, bini, bini};                                        \
  _Pragma("unroll")                                                           \
  for (int ks = 0; ks < 4; ++ks) {                                            \
    ac[0] = MFMA16(Ar##S[ks], x[0][ks], ac[0], 0, 0, 0);                      \
    ac[1] = MFMA16(Ar##S[ks], x[1][ks], ac[1], 0, 0, 0);                      \
    ac[2] = MFMA16(Ar##S[ks], x[2][ks], ac[2], 0, 0, 0);                      \
    ac[3] = MFMA16(Ar##S[ks], x[3][ks], ac[3], 0, 0, 0);                      \
  }                                                                           \
  const int col = (NT) * 16 + 4 * g;                                          \
  _Pragma("unroll")                                                           \
  for (int t = 0; t < 4; ++t) {                                               \
    u32 lo = pkmax0(pkrtz(ac[t][0], ac[t][1]));                               \
    u32 hi = pkmax0(pkrtz(ac[t][2], ac[t][3]));                               \
    if (mode == 1) {                       /* capture vh (already packed) */  \
      vhp[t][NT][0] = lo; vhp[t][NT][1] = hi;                                 \
    } else {                                                                  \
      if (mode == 2) {                     /* h = relu(out) * vh, packed */   \
        lo = pkmul(lo, vhp[t][NT][0]);                                        \
        hi = pkmul(hi, vhp[t][NT][1]);                                        \
      }                                                                       \
      *(uint2*)&X[xr[t] + col] = make_uint2(lo, hi);                          \
    }                                                                         \
  }                                                                           \
} while (0)

// ---------------------------------------------------------------------------
// Main fused kernel — 64 pixels/wave (4 pixel-tiles), asm distance-2 ring:
// 12 loads in flight; WAITV(8) -> COMPUTE -> ISSUE gives each slot two full
// compute steps of latency coverage. Loop body vmem-clean (biases in LDS).
// ---------------------------------------------------------------------------
__global__ __launch_bounds__(256, 2) void rc_main(
    const int*   __restrict__ vert,  const float* __restrict__ bary,
    const float* __restrict__ view,  const float* __restrict__ emb,
    const float* __restrict__ vde_b, const float* __restrict__ vh_b,
    const float* __restrict__ hid_b, const float* __restrict__ head_b0,
    const float* __restrict__ head_b1, const float* __restrict__ head_b2,
    const u16*   __restrict__ ws,    float* __restrict__ out)
{
  __shared__ __align__(16) u16   X[PIXB * RS];   // 69632 B activations
  __shared__ __align__(16) float BL[1664];       // 6656 B: all biases

  const int tid  = threadIdx.x;
  const int lane = tid & 63;
  const int w    = tid >> 6;
  const int r    = lane & 15;       // pixel-within-tile (B col / D col); A row
  const int g    = lane >> 4;       // k-group; D row group
  const int pb   = w * 64;          // wave's first pixel row (64 px/wave)
  const size_t bpix = (size_t)blockIdx.x * PIXB;

  // ---- cooperative bias load into LDS
  for (int i = tid; i < 1664; i += 256) {
    float v;
    if      (i < 128)  v = vde_b[i];
    else if (i < 512)  v = vh_b[i - 128];
    else if (i < 1280) v = hid_b[i - 512];
    else if (i < 1408) v = head_b0[i - 1280];
    else if (i < 1536) v = head_b1[i - 1408];
    else if (i < 1540) v = head_b2[i - 1536];
    else               v = 0.f;
    BL[i] = v;
  }

  // ---- PE: every lane computes its pixel's sin/cos encoding into X[row][0..32)
  {
    const int p = pb + lane;
    const float* vd = view + (bpix + p) * 3;
    const float SG0 = 6.28318530718f;   // 2pi / 0.9^0
    const float SG1 = 6.50777324f;      // 2pi / 0.9^(1/3)
    const float SG2 = 6.74038866f;      // 2pi / 0.9^(2/3)
    u32 pw[16];
#pragma unroll
    for (int i = 0; i < 3; ++i) {
      float x = vd[i];
      float s0 = __sinf(x * SG0), c0 = __cosf(x * SG0);
      float s1 = __sinf(x * SG1), c1 = __cosf(x * SG1);
      float s2 = __sinf(x * SG2), c2 = __cosf(x * SG2);
      pw[i * 3 + 0] = (u32)f2h(s0) | ((u32)f2h(s1) << 16);
      pw[i * 3 + 1] = (u32)f2h(s2) | ((u32)f2h(c0) << 16);
      pw[i * 3 + 2] = (u32)f2h(c1) | ((u32)f2h(c2) << 16);
    }
#pragma unroll
    for (int q = 9; q < 16; ++q) pw[q] = 0u;   // zero-pad k = 18..31
    uint4* dst = (uint4*)&X[p * RS];
#pragma unroll
    for (int q = 0; q < 4; ++q)
      dst[q] = make_uint4(pw[4*q], pw[4*q+1], pw[4*q+2], pw[4*q+3]);
  }
  __syncthreads();   // once; everything below is wave-private in X

  const int xr[4] = { (pb +      r) * RS, (pb + 16 + r) * RS,
                      (pb + 32 + r) * RS, (pb + 48 + r) * RS };
  const u32 aoff  = (u32)(r * RS + g * 8) * 2;   // per-lane A-frag byte offset

  // ---- L0: vde (K=18 padded to 32) — small, compiler-scheduled loads
  {
    h8 Av[8];
#pragma unroll
    for (int nt = 0; nt < 8; ++nt)
      Av[nt] = *(const h8*)&ws[(nt * 16 + r) * PRS + g * 8];
    h8 pe[4];
#pragma unroll
    for (int t = 0; t < 4; ++t) pe[t] = *(const h8*)&X[xr[t] + g * 8];
#pragma unroll
    for (int nt = 0; nt < 8; ++nt) {
      f4 bini = *(const f4*)&BL[nt * 16 + 4 * g];
      const int col = nt * 16 + 4 * g;
#pragma unroll
      for (int t = 0; t < 4; ++t) {
        f4 acc = MFMA16(Av[nt], pe[t], bini, 0, 0, 0);
        *(uint2*)&X[xr[t] + col] =          // no relu on vde output
          make_uint2(pkrtz(acc[0], acc[1]), pkrtz(acc[2], acc[3]));
      }
    }
  }

  // ---- 11 full 128x128 layers: li 0..2 = vh MLP, 3..8 = hidden, 9..10 = head
  u32 vhp[4][8][2];            // captured vh: set at li==2, used at li==5
  h8 Ar0[4], Ar1[4], Ar2[4];   // 3-slot prefetch ring (48 VGPRs)
#pragma unroll 1
  for (int li = 0; li < 11; ++li) {
    const u64 wbase = (u64)(uintptr_t)(ws + WOFF + li * FULL);
    const int blb   = (li + 1) * 128;                     // bias row in BL
    const int mode  = (li == 2) ? 1 : (li == 5) ? 2 : 0;  // 1=capture, 2=modulate

    ISSUE(0, 0);
    ISSUE(1, 1);
    ISSUE(2, 2);                         // 12 loads in flight

    h8 x[4][4];                          // activations read once -> X writable
#pragma unroll
    for (int t = 0; t < 4; ++t)
#pragma unroll
      for (int ks = 0; ks < 4; ++ks)
        x[t][ks] = *(const h8*)&X[xr[t] + ks * 32 + g * 8];

    WAITV("8");  COMPUTE_NT(0, 0);  ISSUE(0, 3);
    WAITV("8");  COMPUTE_NT(1, 1);  ISSUE(1, 4);
    WAITV("8");  COMPUTE_NT(2, 2);  ISSUE(2, 5);
    WAITV("8");  COMPUTE_NT(0, 3);  ISSUE(0, 6);
    WAITV("8");  COMPUTE_NT(1, 4);  ISSUE(1, 7);
    WAITV("8");  COMPUTE_NT(2, 5);
    WAITV("4");  COMPUTE_NT(0, 6);
    WAITV("0");  COMPUTE_NT(1, 7);

    // ---- after vh capture: embedding gather + renorm + bary -> X (vmcnt==0 here)
    if (li == 2) {
#pragma unroll 2
      for (int i = 0; i < 16; ++i) {
        int p = pb + g * 16 + i;               // 16-lane group g handles 16 pixels
        size_t gp = bpix + p;
        const int*   vi = vert + gp * 3;
        const float* by = bary + gp * 3;
        f4 va = {0.f,0.f,0.f,0.f}, vb = {0.f,0.f,0.f,0.f};
#pragma unroll
        for (int vt = 0; vt < 3; ++vt) {
          int id = vi[vt] + 1;
          const float* row = emb + (size_t)id * 128 + r * 8;  // lane r: 8 chans
          f4 e0 = *(const f4*)row;
          f4 e1 = *(const f4*)(row + 4);
          float ss = e0[0]*e0[0] + e0[1]*e0[1] + e0[2]*e0[2] + e0[3]*e0[3]
                   + e1[0]*e1[0] + e1[1]*e1[1] + e1[2]*e1[2] + e1[3]*e1[3];
          ss += __shfl_xor(ss, 1);             // reduce within the 16-lane group
          ss += __shfl_xor(ss, 2);
          ss += __shfl_xor(ss, 4);
          ss += __shfl_xor(ss, 8);
          float nrm = sqrtf(ss);
          float sc  = (nrm > 1.f) ? (1.f / (nrm + 1e-7f)) : 1.f;  // torch max_norm
          float wt  = by[vt] * sc;
#pragma unroll
          for (int j = 0; j < 4; ++j) { va[j] += wt * e0[j]; vb[j] += wt * e1[j]; }
        }
        h8 o;
#pragma unroll
        for (int j = 0; j < 4; ++j) { o[j] = (_Float16)va[j]; o[j+4] = (_Float16)vb[j]; }
        *(h8*)&X[p * RS + r * 8] = o;
      }
    }
    __builtin_amdgcn_s_barrier();   // keep block's waves layer-aligned for L1 reuse
  }

  // ---- head_W2 (128 -> 4) + head_b2, compiler-scheduled (tail, negligible)
  {
    h8 x[4][4];
#pragma unroll
    for (int t = 0; t < 4; ++t)
#pragma unroll
      for (int ks = 0; ks < 4; ++ks)
        x[t][ks] = *(const h8*)&X[xr[t] + ks * 32 + g * 8];
    const u16* wa = ws + WOFF + 11 * FULL;
    f4 b2 = *(const f4*)&BL[1536 + 4 * g];   // g==0 lanes: real head_b2
    f4 acc[4] = {b2, b2, b2, b2};
#pragma unroll
    for (int ks = 0; ks < 4; ++ks) {
      h8 A = *(const h8*)&wa[r * RS + ks * 32 + g * 8];
#pragma unroll
      for (int t = 0; t < 4; ++t)
        acc[t] = MFMA16(A, x[t][ks], acc[t], 0, 0, 0);
    }
    if (g == 0) {                      // lane r holds pixel r's rgba contiguously
#pragma unroll
      for (int t = 0; t < 4; ++t)
        *(f4*)&out[(bpix + pb + t * 16 + r) * 4] = acc[t];
    }
  }
}

// ---------------------------------------------------------------------------
extern "C" void kernel_launch(void* const* d_in, const int* in_sizes, int n_in,
                              void* d_out, int out_size, void* d_ws, size_t ws_size,
                              hipStream_t stream) {
  const int*   vert    = (const int*)  d_in[0];
  const float* bary    = (const float*)d_in[1];
  const float* view    = (const float*)d_in[2];
  const float* emb     = (const float*)d_in[3];
  const float* vde_W   = (const float*)d_in[4];
  const float* vde_b   = (const float*)d_in[5];
  const float* vh_W    = (const float*)d_in[6];
  const float* vh_b    = (const float*)d_in[7];
  const float* hid_W   = (const float*)d_in[8];
  const float* hid_b   = (const float*)d_in[9];
  const float* head_W0 = (const float*)d_in[10];
  const float* head_b0 = (const float*)d_in[11];
  const float* head_W1 = (const float*)d_in[12];
  const float* head_b1 = (const float*)d_in[13];
  const float* head_W2 = (const float*)d_in[14];
  const float* head_b2 = (const float*)d_in[15];
  u16* wsp = (u16*)d_ws;   // needs 428032 B

  rc_prep<<<836, 256, 0, stream>>>(vde_W, vh_W, hid_W, head_W0, head_W1, head_W2, wsp);
  rc_main<<<2048, 256, 0, stream>>>(vert, bary, view, emb, vde_b, vh_b, hid_b,
                                    head_b0, head_b1, head_b2, wsp, (float*)d_out);
}